// Round 2
// baseline (2386.915 us; speedup 1.0000x reference)
//
#include <hip/hip_runtime.h>
#include <math.h>

// Problem constants (B, H, W, C fixed by setup_inputs)
#define B_   8
#define Hs   56
#define Ws   56
#define Cc   768
#define NHh  12
#define HDd  64
#define Nt   3137        // Hs*Ws + 1
#define HW_  3136        // Hs*Ws
#define C3   2304        // 3*Cc
#define SCALE 0.125f     // 1/sqrt(64)

// ---------------------------------------------------------------------------
// Scratch as __device__ globals: allocated at module load. Avoids any
// dependence on ws_size (previous round's abort was consistent with d_ws
// overflow -> GPU page fault). Every element is fully rewritten each call,
// so no state leaks between launches (harness re-poison is irrelevant).
// ---------------------------------------------------------------------------
__device__ float g_qkv[(size_t)B_ * Nt * C3];          // 57,821,184 f (231 MB)
__device__ float g_Ocol[(size_t)B_ * NHh * HW_ * HDd]; // 19,267,584 f (77 MB)
__device__ float g_mcol[(size_t)B_ * NHh * HW_];       //    301,056 f
__device__ float g_lcol[(size_t)B_ * NHh * HW_];       //    301,056 f
__device__ float g_attout[(size_t)B_ * Nt * Cc];       // 19,273,728 f (77 MB)

// ---------------------------------------------------------------------------
// fp32 SGEMM: C[M,Nd] = A[M,K] @ B[K,Nd] (+ bias). 128x128x8 tile, 256 thr,
// 8x8 microtile with split-tile mapping (LDS reads broadcast / 2-way free).
// ---------------------------------------------------------------------------
__global__ __launch_bounds__(256) void sgemm128(
    const float* __restrict__ A, const float* __restrict__ Bm,
    const float* __restrict__ bias, float* __restrict__ Cm,
    int M, int Nd, int K)
{
    __shared__ float As[8][132];   // stored transposed: As[k][m], padded
    __shared__ float Bs[8][132];

    const int tid = threadIdx.x;
    const int tx = tid & 15, ty = tid >> 4;
    const int rowBase = blockIdx.y * 128;
    const int colBase = blockIdx.x * 128;

    const int la_row = tid >> 1;          // 0..127
    const int la_k   = (tid & 1) * 4;     // 0 or 4
    const int lb_k   = tid >> 5;          // 0..7
    const int lb_col = (tid & 31) * 4;    // 0..124

    const int arow = rowBase + la_row;
    const bool aval = arow < M;
    const float* Ap = A + (size_t)(aval ? arow : 0) * K + la_k;
    const float* Bp = Bm + (size_t)lb_k * Nd + colBase + lb_col;
    const size_t bstep = (size_t)8 * Nd;

    float acc[8][8];
#pragma unroll
    for (int i = 0; i < 8; ++i)
#pragma unroll
        for (int j = 0; j < 8; ++j) acc[i][j] = 0.f;

    for (int k0 = 0; k0 < K; k0 += 8) {
        float4 av = aval ? *(const float4*)Ap : make_float4(0.f, 0.f, 0.f, 0.f);
        float4 bv = *(const float4*)Bp;
        Ap += 8;
        Bp += bstep;
        __syncthreads();   // previous iteration's compute done
        As[la_k + 0][la_row] = av.x;
        As[la_k + 1][la_row] = av.y;
        As[la_k + 2][la_row] = av.z;
        As[la_k + 3][la_row] = av.w;
        *(float4*)&Bs[lb_k][lb_col] = bv;
        __syncthreads();
#pragma unroll
        for (int kk = 0; kk < 8; ++kk) {
            float a[8], bb[8];
            *(float4*)&a[0]  = *(const float4*)&As[kk][ty * 4];
            *(float4*)&a[4]  = *(const float4*)&As[kk][64 + ty * 4];
            *(float4*)&bb[0] = *(const float4*)&Bs[kk][tx * 4];
            *(float4*)&bb[4] = *(const float4*)&Bs[kk][64 + tx * 4];
#pragma unroll
            for (int i = 0; i < 8; ++i)
#pragma unroll
                for (int j = 0; j < 8; ++j)
                    acc[i][j] = fmaf(a[i], bb[j], acc[i][j]);
        }
    }

    float bvals[8];
#pragma unroll
    for (int j = 0; j < 8; ++j) {
        int col = colBase + ((j < 4) ? (tx * 4 + j) : (64 + tx * 4 + j - 4));
        bvals[j] = bias ? bias[col] : 0.f;
    }
#pragma unroll
    for (int i = 0; i < 8; ++i) {
        int row = rowBase + ((i < 4) ? (ty * 4 + i) : (64 + ty * 4 + i - 4));
        if (row < M) {
            float4 o0 = make_float4(acc[i][0] + bvals[0], acc[i][1] + bvals[1],
                                    acc[i][2] + bvals[2], acc[i][3] + bvals[3]);
            float4 o1 = make_float4(acc[i][4] + bvals[4], acc[i][5] + bvals[5],
                                    acc[i][6] + bvals[6], acc[i][7] + bvals[7]);
            *(float4*)&Cm[(size_t)row * Nd + colBase + tx * 4]      = o0;
            *(float4*)&Cm[(size_t)row * Nd + colBase + 64 + tx * 4] = o1;
        }
    }
}

// ---------------------------------------------------------------------------
// Column attention partials: block per (w, head, b). Keys = cls + column(w)
// (1+H = 57 keys). One thread per query row h. Online softmax; writes
// unnormalized O, running max m, running sum l.
// qkv layout: [b][n][s(3)][nh][hd], i.e. (b*Nt+n)*C3 + s*Cc + nh*64 + d
// ---------------------------------------------------------------------------
__global__ __launch_bounds__(64) void col_attn(
    const float* __restrict__ qkv, float* __restrict__ Ocol,
    float* __restrict__ mcol, float* __restrict__ lcol)
{
    const int w = blockIdx.x, nh = blockIdx.y, b = blockIdx.z;
    __shared__ float Kc[57 * HDd];
    __shared__ float Vc[57 * HDd];
    const int tid = threadIdx.x;

    for (int e = tid; e < 57 * 16; e += 64) {
        int j = e >> 4, d4 = e & 15;
        int n = (j == 0) ? 0 : ((j - 1) * Ws + w + 1);
        const float* base = qkv + (size_t)(b * Nt + n) * C3 + nh * HDd + d4 * 4;
        ((float4*)Kc)[e] = *(const float4*)(base + Cc);
        ((float4*)Vc)[e] = *(const float4*)(base + 2 * Cc);
    }
    __syncthreads();

    if (tid < Hs) {
        const int h = tid;
        const int n = h * Ws + w + 1;
        const float* qp = qkv + (size_t)(b * Nt + n) * C3 + nh * HDd;
        float q[HDd];
#pragma unroll
        for (int d4 = 0; d4 < 16; ++d4)
            *(float4*)&q[d4 * 4] = *(const float4*)(qp + d4 * 4);

        float m = -INFINITY, l = 0.f, O[HDd];
#pragma unroll
        for (int d = 0; d < HDd; ++d) O[d] = 0.f;

        for (int j = 0; j <= Hs; ++j) {
            float s = 0.f;
#pragma unroll
            for (int d = 0; d < HDd; ++d) s = fmaf(q[d], Kc[j * HDd + d], s);
            s *= SCALE;
            float mn = fmaxf(m, s);
            float corr = __expf(m - mn);   // exp(-inf)=0 on first iter
            float p = __expf(s - mn);
            l = l * corr + p;
#pragma unroll
            for (int d = 0; d < HDd; ++d)
                O[d] = fmaf(O[d], corr, p * Vc[j * HDd + d]);
            m = mn;
        }
        const size_t qi = (size_t)((b * NHh + nh) * HW_ + h * Ws + w);
        mcol[qi] = m;
        lcol[qi] = l;
#pragma unroll
        for (int d4 = 0; d4 < 16; ++d4)
            *(float4*)&Ocol[qi * HDd + d4 * 4] = *(float4*)&O[d4 * 4];
    }
}

// ---------------------------------------------------------------------------
// Row attention + merge: block per (h, head, b). Keys = row(h), self masked.
// One thread per query col w. Merges with column partials, writes att_out
// in (B, N, C) layout ready for GEMM2.
// ---------------------------------------------------------------------------
__global__ __launch_bounds__(64) void row_attn_merge(
    const float* __restrict__ qkv, const float* __restrict__ Ocol,
    const float* __restrict__ mcol, const float* __restrict__ lcol,
    float* __restrict__ attout)
{
    const int h = blockIdx.x, nh = blockIdx.y, b = blockIdx.z;
    __shared__ float Kr[Ws * HDd];
    __shared__ float Vr[Ws * HDd];
    const int tid = threadIdx.x;

    for (int e = tid; e < Ws * 16; e += 64) {
        int j = e >> 4, d4 = e & 15;
        int n = h * Ws + j + 1;
        const float* base = qkv + (size_t)(b * Nt + n) * C3 + nh * HDd + d4 * 4;
        ((float4*)Kr)[e] = *(const float4*)(base + Cc);
        ((float4*)Vr)[e] = *(const float4*)(base + 2 * Cc);
    }
    __syncthreads();

    if (tid < Ws) {
        const int w = tid;
        const int n = h * Ws + w + 1;
        const float* qp = qkv + (size_t)(b * Nt + n) * C3 + nh * HDd;
        float q[HDd];
#pragma unroll
        for (int d4 = 0; d4 < 16; ++d4)
            *(float4*)&q[d4 * 4] = *(const float4*)(qp + d4 * 4);

        float m = -INFINITY, l = 0.f, O[HDd];
#pragma unroll
        for (int d = 0; d < HDd; ++d) O[d] = 0.f;

        for (int j = 0; j < Ws; ++j) {
            if (j == w) continue;   // diagonal masked -inf
            float s = 0.f;
#pragma unroll
            for (int d = 0; d < HDd; ++d) s = fmaf(q[d], Kr[j * HDd + d], s);
            s *= SCALE;
            float mn = fmaxf(m, s);
            float corr = __expf(m - mn);
            float p = __expf(s - mn);
            l = l * corr + p;
#pragma unroll
            for (int d = 0; d < HDd; ++d)
                O[d] = fmaf(O[d], corr, p * Vr[j * HDd + d]);
            m = mn;
        }

        const size_t qi = (size_t)((b * NHh + nh) * HW_ + h * Ws + w);
        const float mc = mcol[qi], lc = lcol[qi];
        const float mn = fmaxf(mc, m);
        const float fc = __expf(mc - mn);
        const float fr = __expf(m - mn);
        const float inv = 1.f / (lc * fc + l * fr);
        float* op = attout + (size_t)(b * Nt + n) * Cc + nh * HDd;
        const float* ocp = Ocol + qi * HDd;
#pragma unroll
        for (int d4 = 0; d4 < 16; ++d4) {
            float4 oc = *(const float4*)(ocp + d4 * 4);
            float4 orow = *(float4*)&O[d4 * 4];
            float4 r;
            r.x = (oc.x * fc + orow.x * fr) * inv;
            r.y = (oc.y * fc + orow.y * fr) * inv;
            r.z = (oc.z * fc + orow.z * fr) * inv;
            r.w = (oc.w * fc + orow.w * fr) * inv;
            *(float4*)(op + d4 * 4) = r;
        }
    }
}

// ---------------------------------------------------------------------------
// Cls-token attention: block per (head, b), 4 waves. Each wave strides over
// the N keys; lane d holds dim d. Cross-lane shuffle-reduce for scores,
// LDS merge of the 4 per-wave online-softmax states.
// ---------------------------------------------------------------------------
__global__ __launch_bounds__(256) void cls_attn(
    const float* __restrict__ qkv, float* __restrict__ attout)
{
    const int nh = blockIdx.x, b = blockIdx.y;
    const int tid = threadIdx.x;
    const int lane = tid & 63, wv = tid >> 6;

    const float qd = qkv[(size_t)(b * Nt) * C3 + nh * HDd + lane];
    float m = -INFINITY, l = 0.f, Od = 0.f;

    for (int j = wv; j < Nt; j += 4) {
        const float* base = qkv + (size_t)(b * Nt + j) * C3 + nh * HDd;
        float prod = qd * base[Cc + lane];
#pragma unroll
        for (int off = 32; off >= 1; off >>= 1)
            prod += __shfl_xor(prod, off, 64);
        float s = prod * SCALE;
        float mn = fmaxf(m, s);
        float corr = __expf(m - mn);
        float p = __expf(s - mn);
        l = l * corr + p;
        Od = fmaf(Od, corr, p * base[2 * Cc + lane]);
        m = mn;
    }

    __shared__ float sm[4], sl[4], sO[4][64];
    if (lane == 0) { sm[wv] = m; sl[wv] = l; }
    sO[wv][lane] = Od;
    __syncthreads();

    if (tid < 64) {
        float M2 = fmaxf(fmaxf(sm[0], sm[1]), fmaxf(sm[2], sm[3]));
        float L = 0.f, OO = 0.f;
#pragma unroll
        for (int i = 0; i < 4; ++i) {
            float f = __expf(sm[i] - M2);
            L += sl[i] * f;
            OO += sO[i][tid] * f;
        }
        attout[(size_t)(b * Nt) * Cc + nh * HDd + tid] = OO / L;
    }
}

// ---------------------------------------------------------------------------
extern "C" void kernel_launch(void* const* d_in, const int* in_sizes, int n_in,
                              void* d_out, int out_size, void* d_ws, size_t ws_size,
                              hipStream_t stream)
{
    const float* x     = (const float*)d_in[0];
    const float* Wqkv  = (const float*)d_in[1];
    const float* Wproj = (const float*)d_in[2];
    const float* bproj = (const float*)d_in[3];
    float* out = (float*)d_out;

    float* qkv;    hipGetSymbolAddress((void**)&qkv,    HIP_SYMBOL(g_qkv));
    float* Ocol;   hipGetSymbolAddress((void**)&Ocol,   HIP_SYMBOL(g_Ocol));
    float* mcol;   hipGetSymbolAddress((void**)&mcol,   HIP_SYMBOL(g_mcol));
    float* lcol;   hipGetSymbolAddress((void**)&lcol,   HIP_SYMBOL(g_lcol));
    float* attout; hipGetSymbolAddress((void**)&attout, HIP_SYMBOL(g_attout));

    const int M = B_ * Nt;   // 25096

    // 1) qkv = x @ W_qkv
    dim3 g1(C3 / 128, (M + 127) / 128);
    sgemm128<<<g1, 256, 0, stream>>>(x, Wqkv, nullptr, qkv, M, C3, Cc);

    // 2a) column-attention partials
    col_attn<<<dim3(Ws, NHh, B_), 64, 0, stream>>>(qkv, Ocol, mcol, lcol);

    // 2b) cls-token attention (independent of 2a)
    cls_attn<<<dim3(NHh, B_), 256, 0, stream>>>(qkv, attout);

    // 2c) row attention + merge -> attout
    row_attn_merge<<<dim3(Hs, NHh, B_), 64, 0, stream>>>(qkv, Ocol, mcol, lcol, attout);

    // 3) out = attout @ W_proj + b_proj
    dim3 g2(Cc / 128, (M + 127) / 128);
    sgemm128<<<g2, 256, 0, stream>>>(attout, Wproj, bproj, out, M, Cc, Cc);
}

// Round 3
// 1077.909 us; speedup vs baseline: 2.2144x; 2.2144x over previous
//
#include <hip/hip_runtime.h>
#include <math.h>

#define B_   8
#define Hs   56
#define Ws   56
#define Cc   768
#define NHh  12
#define HDd  64
#define Nt   3137
#define HW_  3136
#define C3   2304
#define SCALE 0.125f
#define Mrows (B_ * Nt)        // 25096
#define Mpad  (197 * 128)      // 25216 (197 row-blocks of 128)

typedef _Float16 half8 __attribute__((ext_vector_type(8)));
typedef _Float16 half4 __attribute__((ext_vector_type(4)));
typedef float floatx4 __attribute__((ext_vector_type(4)));

// ---------------- scratch (__device__ globals; ws_size-independent) --------
__device__ float    g_qkv[(size_t)Mrows * C3];           // fp32 qkv (231 MB)
__device__ float    g_Ocol[(size_t)B_ * NHh * HW_ * HDd];
__device__ float    g_mcol[(size_t)B_ * NHh * HW_];
__device__ float    g_lcol[(size_t)B_ * NHh * HW_];
__device__ _Float16 g_xh[(size_t)Mpad * Cc];             // x in fp16, padded rows
__device__ _Float16 g_attH[(size_t)Mpad * Cc];           // attention out fp16, padded
__device__ _Float16 g_WqkvT[(size_t)C3 * Cc];            // Wqkv^T fp16 [2304][768]
__device__ _Float16 g_WprojT[(size_t)Cc * Cc];           // Wproj^T fp16 [768][768]

// ---------------- fp32 -> fp16 convert (row-major copy) --------------------
__global__ __launch_bounds__(256) void cvt_f16(
    const float* __restrict__ in, _Float16* __restrict__ out, int n4)
{
    for (int i = blockIdx.x * 256 + threadIdx.x; i < n4; i += gridDim.x * 256) {
        float4 v = ((const float4*)in)[i];
        half4 h = { (_Float16)v.x, (_Float16)v.y, (_Float16)v.z, (_Float16)v.w };
        ((half4*)out)[i] = h;
    }
}

// ---------------- fp32 [R][Cq] -> fp16 transposed [Cq][R] ------------------
__global__ __launch_bounds__(256) void transpose_f16(
    const float* __restrict__ in, _Float16* __restrict__ out, int R, int Cq)
{
    __shared__ float t[32][33];
    const int c0 = blockIdx.x * 32, r0 = blockIdx.y * 32;
    const int tx = threadIdx.x & 31, ty = threadIdx.x >> 5;  // 32x8
#pragma unroll
    for (int i = 0; i < 32; i += 8)
        t[ty + i][tx] = in[(size_t)(r0 + ty + i) * Cq + c0 + tx];
    __syncthreads();
#pragma unroll
    for (int i = 0; i < 32; i += 8)
        out[(size_t)(c0 + ty + i) * R + r0 + tx] = (_Float16)t[tx][ty + i];
}

// ---------------------------------------------------------------------------
// fp16 MFMA GEMM (m97 structure): C[M,Nd] = A[Mpad,K] @ Bt[Nd,K]^T (+bias).
// 128x128 tile, BK=32, 4 waves each 64x64 via 4x4 of mfma_f32_16x16x32_f16.
// Staging via global_load_lds width 16; A rows must be padded (no guards).
// ---------------------------------------------------------------------------
__global__ __launch_bounds__(256) void gemm_f16(
    const _Float16* __restrict__ A, const _Float16* __restrict__ Bt,
    const float* __restrict__ bias, float* __restrict__ Cm,
    int M, int Nd, int K)
{
    __shared__ _Float16 Ah[128 * 32];   // [m][k]
    __shared__ _Float16 Bh[128 * 32];   // [n][k]
    const int tid = threadIdx.x;
    const int wave = tid >> 6, lane = tid & 63;
    const int wm = wave & 1, wn = wave >> 1;
    const int mBase = blockIdx.y * 128, nBase = blockIdx.x * 128;

    const int u0 = wave * 128 + lane;   // staging unit t=0 (u1 = u0+64)
    const int u1 = u0 + 64;
    const _Float16* ga0 = A + (size_t)(mBase + (u0 >> 2)) * K + (u0 & 3) * 8;
    const _Float16* ga1 = A + (size_t)(mBase + (u1 >> 2)) * K + (u1 & 3) * 8;
    const _Float16* gb0 = Bt + (size_t)(nBase + (u0 >> 2)) * K + (u0 & 3) * 8;
    const _Float16* gb1 = Bt + (size_t)(nBase + (u1 >> 2)) * K + (u1 & 3) * 8;
    _Float16* la0 = &Ah[(size_t)(wave * 128) * 8];
    _Float16* la1 = &Ah[(size_t)(wave * 128 + 64) * 8];
    _Float16* lb0 = &Bh[(size_t)(wave * 128) * 8];
    _Float16* lb1 = &Bh[(size_t)(wave * 128 + 64) * 8];

    const int aoff = (wm * 64 + (lane & 15)) * 32 + (lane >> 4) * 8;
    const int boff = (wn * 64 + (lane & 15)) * 32 + (lane >> 4) * 8;

    floatx4 acc[4][4] = {};

    for (int k0 = 0; k0 < K; k0 += 32) {
        __syncthreads();
        __builtin_amdgcn_global_load_lds((const __attribute__((address_space(1))) void*)ga0,
                                         (__attribute__((address_space(3))) void*)la0, 16, 0, 0);
        __builtin_amdgcn_global_load_lds((const __attribute__((address_space(1))) void*)ga1,
                                         (__attribute__((address_space(3))) void*)la1, 16, 0, 0);
        __builtin_amdgcn_global_load_lds((const __attribute__((address_space(1))) void*)gb0,
                                         (__attribute__((address_space(3))) void*)lb0, 16, 0, 0);
        __builtin_amdgcn_global_load_lds((const __attribute__((address_space(1))) void*)gb1,
                                         (__attribute__((address_space(3))) void*)lb1, 16, 0, 0);
        ga0 += 32; ga1 += 32; gb0 += 32; gb1 += 32;
        __syncthreads();

        half8 a[4], b[4];
#pragma unroll
        for (int mi = 0; mi < 4; ++mi) a[mi] = *(const half8*)&Ah[aoff + mi * 512];
#pragma unroll
        for (int ni = 0; ni < 4; ++ni) b[ni] = *(const half8*)&Bh[boff + ni * 512];
#pragma unroll
        for (int mi = 0; mi < 4; ++mi)
#pragma unroll
            for (int ni = 0; ni < 4; ++ni)
                acc[mi][ni] = __builtin_amdgcn_mfma_f32_16x16x32_f16(
                    a[mi], b[ni], acc[mi][ni], 0, 0, 0);
    }

    // C/D layout: col = lane&15, row = (lane>>4)*4 + reg
    const int colb = nBase + wn * 64 + (lane & 15);
    const int rowb = mBase + wm * 64 + (lane >> 4) * 4;
#pragma unroll
    for (int ni = 0; ni < 4; ++ni) {
        const int col = colb + ni * 16;
        const float bv = bias ? bias[col] : 0.f;
#pragma unroll
        for (int mi = 0; mi < 4; ++mi) {
#pragma unroll
            for (int r = 0; r < 4; ++r) {
                const int row = rowb + mi * 16 + r;
                if (row < M) Cm[(size_t)row * Nd + col] = acc[mi][ni][r] + bv;
            }
        }
    }
}

// ---------------------------------------------------------------------------
// Column attention partials (float4 LDS reads)
// ---------------------------------------------------------------------------
__global__ __launch_bounds__(64) void col_attn(
    const float* __restrict__ qkv, float* __restrict__ Ocol,
    float* __restrict__ mcol, float* __restrict__ lcol)
{
    const int w = blockIdx.x, nh = blockIdx.y, b = blockIdx.z;
    __shared__ float Kc[57 * HDd];
    __shared__ float Vc[57 * HDd];
    const int tid = threadIdx.x;

    for (int e = tid; e < 57 * 16; e += 64) {
        int j = e >> 4, d4 = e & 15;
        int n = (j == 0) ? 0 : ((j - 1) * Ws + w + 1);
        const float* base = qkv + (size_t)(b * Nt + n) * C3 + nh * HDd + d4 * 4;
        ((float4*)Kc)[e] = *(const float4*)(base + Cc);
        ((float4*)Vc)[e] = *(const float4*)(base + 2 * Cc);
    }
    __syncthreads();

    if (tid < Hs) {
        const int h = tid;
        const int n = h * Ws + w + 1;
        const float* qp = qkv + (size_t)(b * Nt + n) * C3 + nh * HDd;
        float4 q4[16];
#pragma unroll
        for (int d4 = 0; d4 < 16; ++d4) q4[d4] = *(const float4*)(qp + d4 * 4);

        float m = -INFINITY, l = 0.f;
        float4 O4[16] = {};

        for (int j = 0; j <= Hs; ++j) {
            const float4* kp = (const float4*)&Kc[j * HDd];
            float s0 = 0.f, s1 = 0.f, s2 = 0.f, s3 = 0.f;
#pragma unroll
            for (int d4 = 0; d4 < 16; ++d4) {
                float4 kk = kp[d4];
                s0 = fmaf(q4[d4].x, kk.x, s0);
                s1 = fmaf(q4[d4].y, kk.y, s1);
                s2 = fmaf(q4[d4].z, kk.z, s2);
                s3 = fmaf(q4[d4].w, kk.w, s3);
            }
            float s = ((s0 + s1) + (s2 + s3)) * SCALE;
            float mn = fmaxf(m, s);
            float corr = __expf(m - mn);
            float p = __expf(s - mn);
            l = l * corr + p;
            const float4* vp = (const float4*)&Vc[j * HDd];
#pragma unroll
            for (int d4 = 0; d4 < 16; ++d4) {
                float4 vv = vp[d4];
                O4[d4].x = fmaf(O4[d4].x, corr, p * vv.x);
                O4[d4].y = fmaf(O4[d4].y, corr, p * vv.y);
                O4[d4].z = fmaf(O4[d4].z, corr, p * vv.z);
                O4[d4].w = fmaf(O4[d4].w, corr, p * vv.w);
            }
            m = mn;
        }
        const size_t qi = (size_t)((b * NHh + nh) * HW_ + h * Ws + w);
        mcol[qi] = m;
        lcol[qi] = l;
#pragma unroll
        for (int d4 = 0; d4 < 16; ++d4)
            *(float4*)&Ocol[qi * HDd + d4 * 4] = O4[d4];
    }
}

// ---------------------------------------------------------------------------
// Row attention + merge -> attH (fp16, [Mpad][768] row-major)
// ---------------------------------------------------------------------------
__global__ __launch_bounds__(64) void row_attn_merge(
    const float* __restrict__ qkv, const float* __restrict__ Ocol,
    const float* __restrict__ mcol, const float* __restrict__ lcol,
    _Float16* __restrict__ attH)
{
    const int h = blockIdx.x, nh = blockIdx.y, b = blockIdx.z;
    __shared__ float Kr[Ws * HDd];
    __shared__ float Vr[Ws * HDd];
    const int tid = threadIdx.x;

    for (int e = tid; e < Ws * 16; e += 64) {
        int j = e >> 4, d4 = e & 15;
        int n = h * Ws + j + 1;
        const float* base = qkv + (size_t)(b * Nt + n) * C3 + nh * HDd + d4 * 4;
        ((float4*)Kr)[e] = *(const float4*)(base + Cc);
        ((float4*)Vr)[e] = *(const float4*)(base + 2 * Cc);
    }
    __syncthreads();

    if (tid < Ws) {
        const int w = tid;
        const int n = h * Ws + w + 1;
        const float* qp = qkv + (size_t)(b * Nt + n) * C3 + nh * HDd;
        float4 q4[16];
#pragma unroll
        for (int d4 = 0; d4 < 16; ++d4) q4[d4] = *(const float4*)(qp + d4 * 4);

        float m = -INFINITY, l = 0.f;
        float4 O4[16] = {};

        for (int j = 0; j < Ws; ++j) {
            if (j == w) continue;   // diagonal masked
            const float4* kp = (const float4*)&Kr[j * HDd];
            float s0 = 0.f, s1 = 0.f, s2 = 0.f, s3 = 0.f;
#pragma unroll
            for (int d4 = 0; d4 < 16; ++d4) {
                float4 kk = kp[d4];
                s0 = fmaf(q4[d4].x, kk.x, s0);
                s1 = fmaf(q4[d4].y, kk.y, s1);
                s2 = fmaf(q4[d4].z, kk.z, s2);
                s3 = fmaf(q4[d4].w, kk.w, s3);
            }
            float s = ((s0 + s1) + (s2 + s3)) * SCALE;
            float mn = fmaxf(m, s);
            float corr = __expf(m - mn);
            float p = __expf(s - mn);
            l = l * corr + p;
            const float4* vp = (const float4*)&Vr[j * HDd];
#pragma unroll
            for (int d4 = 0; d4 < 16; ++d4) {
                float4 vv = vp[d4];
                O4[d4].x = fmaf(O4[d4].x, corr, p * vv.x);
                O4[d4].y = fmaf(O4[d4].y, corr, p * vv.y);
                O4[d4].z = fmaf(O4[d4].z, corr, p * vv.z);
                O4[d4].w = fmaf(O4[d4].w, corr, p * vv.w);
            }
            m = mn;
        }

        const size_t qi = (size_t)((b * NHh + nh) * HW_ + h * Ws + w);
        const float mc = mcol[qi], lc = lcol[qi];
        const float mn = fmaxf(mc, m);
        const float fc = __expf(mc - mn);
        const float fr = __expf(m - mn);
        const float inv = 1.f / (lc * fc + l * fr);
        _Float16* op = attH + (size_t)(b * Nt + n) * Cc + nh * HDd;
        const float* ocp = Ocol + qi * HDd;
#pragma unroll
        for (int d4 = 0; d4 < 16; ++d4) {
            float4 oc = *(const float4*)(ocp + d4 * 4);
            half4 r = { (_Float16)((oc.x * fc + O4[d4].x * fr) * inv),
                        (_Float16)((oc.y * fc + O4[d4].y * fr) * inv),
                        (_Float16)((oc.z * fc + O4[d4].z * fr) * inv),
                        (_Float16)((oc.w * fc + O4[d4].w * fr) * inv) };
            *(half4*)(op + d4 * 4) = r;
        }
    }
}

// ---------------------------------------------------------------------------
// Cls-token attention: block per (head, b), 16 waves.
// ---------------------------------------------------------------------------
__global__ __launch_bounds__(1024) void cls_attn(
    const float* __restrict__ qkv, _Float16* __restrict__ attH)
{
    const int nh = blockIdx.x, b = blockIdx.y;
    const int tid = threadIdx.x;
    const int lane = tid & 63, wv = tid >> 6;

    const float qd = qkv[(size_t)(b * Nt) * C3 + nh * HDd + lane];
    float m = -INFINITY, l = 0.f, Od = 0.f;

    for (int j = wv; j < Nt; j += 16) {
        const float* base = qkv + (size_t)(b * Nt + j) * C3 + nh * HDd;
        float prod = qd * base[Cc + lane];
#pragma unroll
        for (int off = 32; off >= 1; off >>= 1)
            prod += __shfl_xor(prod, off, 64);
        float s = prod * SCALE;
        float mn = fmaxf(m, s);
        float corr = __expf(m - mn);
        float p = __expf(s - mn);
        l = l * corr + p;
        Od = fmaf(Od, corr, p * base[2 * Cc + lane]);
        m = mn;
    }

    __shared__ float sm[16], sl[16], sO[16][64];
    if (lane == 0) { sm[wv] = m; sl[wv] = l; }
    sO[wv][lane] = Od;
    __syncthreads();

    if (tid < 64) {
        float M2 = sm[0];
#pragma unroll
        for (int i = 1; i < 16; ++i) M2 = fmaxf(M2, sm[i]);
        float L = 0.f, OO = 0.f;
#pragma unroll
        for (int i = 0; i < 16; ++i) {
            float f = __expf(sm[i] - M2);
            L += sl[i] * f;
            OO += sO[i][tid] * f;
        }
        attH[(size_t)(b * Nt) * Cc + nh * HDd + tid] = (_Float16)(OO / L);
    }
}

// ---------------------------------------------------------------------------
extern "C" void kernel_launch(void* const* d_in, const int* in_sizes, int n_in,
                              void* d_out, int out_size, void* d_ws, size_t ws_size,
                              hipStream_t stream)
{
    const float* x     = (const float*)d_in[0];
    const float* Wqkv  = (const float*)d_in[1];
    const float* Wproj = (const float*)d_in[2];
    const float* bproj = (const float*)d_in[3];
    float* out = (float*)d_out;

    float*    qkv;    hipGetSymbolAddress((void**)&qkv,    HIP_SYMBOL(g_qkv));
    float*    Ocol;   hipGetSymbolAddress((void**)&Ocol,   HIP_SYMBOL(g_Ocol));
    float*    mcol;   hipGetSymbolAddress((void**)&mcol,   HIP_SYMBOL(g_mcol));
    float*    lcol;   hipGetSymbolAddress((void**)&lcol,   HIP_SYMBOL(g_lcol));
    _Float16* xh;     hipGetSymbolAddress((void**)&xh,     HIP_SYMBOL(g_xh));
    _Float16* attH;   hipGetSymbolAddress((void**)&attH,   HIP_SYMBOL(g_attH));
    _Float16* WqkvT;  hipGetSymbolAddress((void**)&WqkvT,  HIP_SYMBOL(g_WqkvT));
    _Float16* WprojT; hipGetSymbolAddress((void**)&WprojT, HIP_SYMBOL(g_WprojT));

    // 0) precision prep: x -> fp16, weights -> fp16 transposed [N][K]
    cvt_f16<<<4096, 256, 0, stream>>>(x, xh, (Mrows * Cc) / 4);
    transpose_f16<<<dim3(C3 / 32, Cc / 32), 256, 0, stream>>>(Wqkv, WqkvT, Cc, C3);
    transpose_f16<<<dim3(Cc / 32, Cc / 32), 256, 0, stream>>>(Wproj, WprojT, Cc, Cc);

    // 1) qkv = x @ W_qkv   (fp16 MFMA, fp32 out)
    gemm_f16<<<dim3(C3 / 128, Mpad / 128), 256, 0, stream>>>(
        xh, WqkvT, nullptr, qkv, Mrows, C3, Cc);

    // 2) attention
    col_attn<<<dim3(Ws, NHh, B_), 64, 0, stream>>>(qkv, Ocol, mcol, lcol);
    cls_attn<<<dim3(NHh, B_), 1024, 0, stream>>>(qkv, attH);
    row_attn_merge<<<dim3(Hs, NHh, B_), 64, 0, stream>>>(qkv, Ocol, mcol, lcol, attH);

    // 3) out = attH @ W_proj + b_proj   (fp16 MFMA, fp32 out)
    gemm_f16<<<dim3(Cc / 128, Mpad / 128), 256, 0, stream>>>(
        attH, WprojT, bproj, out, Mrows, Cc, Cc);
}

// Round 4
// 712.209 us; speedup vs baseline: 3.3514x; 1.5135x over previous
//
#include <hip/hip_runtime.h>
#include <math.h>

#define B_   8
#define Hs   56
#define Ws   56
#define Cc   768
#define NHh  12
#define HDd  64
#define Nt   3137
#define HW_  3136
#define C3   2304
#define SCALE 0.125f
#define Mrows (B_ * Nt)        // 25096
#define Mpad  (197 * 128)      // 25216

typedef _Float16 half8  __attribute__((ext_vector_type(8)));
typedef _Float16 half4  __attribute__((ext_vector_type(4)));
typedef _Float16 half2_ __attribute__((ext_vector_type(2)));
typedef float floatx4 __attribute__((ext_vector_type(4)));

__device__ inline float fdot2f(half2_ a, half2_ b, float c) {
#if __has_builtin(__builtin_amdgcn_fdot2)
    return __builtin_amdgcn_fdot2(a, b, c, false);
#else
    return fmaf((float)a.x, (float)b.x, fmaf((float)a.y, (float)b.y, c));
#endif
}

// ---------------- scratch (__device__ globals) -----------------------------
__device__ _Float16 g_qkvh[(size_t)Mrows * C3];          // fp16 qkv (115 MB)
__device__ float    g_Ocol[(size_t)B_ * NHh * HW_ * HDd];
__device__ float    g_mcol[(size_t)B_ * NHh * HW_];
__device__ float    g_lcol[(size_t)B_ * NHh * HW_];
__device__ _Float16 g_xh[(size_t)Mpad * Cc];
__device__ _Float16 g_attH[(size_t)Mpad * Cc];
__device__ _Float16 g_WqkvT[(size_t)C3 * Cc];
__device__ _Float16 g_WprojT[(size_t)Cc * Cc];
__device__ float    g_clsP[(size_t)B_ * NHh * 4 * 66];   // per-partial: m,l,O[64]

// ---------------- fp32 -> fp16 convert -------------------------------------
__global__ __launch_bounds__(256) void cvt_f16(
    const float* __restrict__ in, _Float16* __restrict__ out, int n4)
{
    for (int i = blockIdx.x * 256 + threadIdx.x; i < n4; i += gridDim.x * 256) {
        float4 v = ((const float4*)in)[i];
        half4 h = { (_Float16)v.x, (_Float16)v.y, (_Float16)v.z, (_Float16)v.w };
        ((half4*)out)[i] = h;
    }
}

// ---------------- fp32 [R][Cq] -> fp16 transposed [Cq][R] ------------------
__global__ __launch_bounds__(256) void transpose_f16(
    const float* __restrict__ in, _Float16* __restrict__ out, int R, int Cq)
{
    __shared__ float t[32][33];
    const int c0 = blockIdx.x * 32, r0 = blockIdx.y * 32;
    const int tx = threadIdx.x & 31, ty = threadIdx.x >> 5;
#pragma unroll
    for (int i = 0; i < 32; i += 8)
        t[ty + i][tx] = in[(size_t)(r0 + ty + i) * Cq + c0 + tx];
    __syncthreads();
#pragma unroll
    for (int i = 0; i < 32; i += 8)
        out[(size_t)(c0 + ty + i) * R + r0 + tx] = (_Float16)t[tx][ty + i];
}

// ---------------------------------------------------------------------------
// fp16 MFMA GEMM: C[M,Nd] = A[Mpad,K] @ Bt[Nd,K]^T (+bias).
// 128x128 tile, BK=32. Swizzled LDS staging (conflict-free b128 fragment
// reads), swapped-operand MFMA so the epilogue stores half4/float4 along n.
// 16-row panel swizzle of block index for L2 reuse of the B panel.
// ---------------------------------------------------------------------------
template <typename OutT>
__global__ __launch_bounds__(256) void gemm_f16(
    const _Float16* __restrict__ A, const _Float16* __restrict__ Bt,
    const float* __restrict__ bias, OutT* __restrict__ Cm,
    int M, int Nd, int K)
{
    __shared__ _Float16 Ah[128 * 32];
    __shared__ _Float16 Bh[128 * 32];
    const int tid = threadIdx.x;
    const int wave = tid >> 6, lane = tid & 63;
    const int wm = wave & 1, wn = wave >> 1;

    // panel swizzle: 16 row-blocks per panel, col-major within panel
    const int bid = blockIdx.y * gridDim.x + blockIdx.x;
    const int perPanel = gridDim.x * 16;
    const int panel = bid / perPanel;
    const int rowsIn = min(16, (int)gridDim.y - panel * 16);
    const int rem = bid - panel * perPanel;
    const int by = panel * 16 + rem % rowsIn;
    const int bx = rem / rowsIn;
    const int mBase = by * 128, nBase = bx * 128;

    // staging: unit u in [0,512) -> row m=(u>>6)*16+(u&15), kchunk=(u>>4)&3,
    // LDS offset u*16B (conflict-free fragment layout by construction)
    const int u0 = wave * 128 + lane, u1 = u0 + 64;
    const int m0 = ((u0 >> 6) << 4) + (u0 & 15), kc0 = (u0 >> 4) & 3;
    const int m1 = ((u1 >> 6) << 4) + (u1 & 15), kc1 = (u1 >> 4) & 3;
    const _Float16* ga0 = A + (size_t)(mBase + m0) * K + kc0 * 8;
    const _Float16* ga1 = A + (size_t)(mBase + m1) * K + kc1 * 8;
    const _Float16* gb0 = Bt + (size_t)(nBase + m0) * K + kc0 * 8;
    const _Float16* gb1 = Bt + (size_t)(nBase + m1) * K + kc1 * 8;
    _Float16* la0 = &Ah[(u0 >> 6) * 512];
    _Float16* la1 = &Ah[(u1 >> 6) * 512];
    _Float16* lb0 = &Bh[(u0 >> 6) * 512];
    _Float16* lb1 = &Bh[(u1 >> 6) * 512];

    // fragment offsets (halfs): (m>>4)*512 + kq*128 + (m&15)*8
    const int aoff = wm * 2048 + (lane >> 4) * 128 + (lane & 15) * 8;
    const int boff = wn * 2048 + (lane >> 4) * 128 + (lane & 15) * 8;

    floatx4 acc[4][4] = {};

    for (int k0 = 0; k0 < K; k0 += 32) {
        __syncthreads();
        __builtin_amdgcn_global_load_lds((const __attribute__((address_space(1))) void*)ga0,
                                         (__attribute__((address_space(3))) void*)la0, 16, 0, 0);
        __builtin_amdgcn_global_load_lds((const __attribute__((address_space(1))) void*)ga1,
                                         (__attribute__((address_space(3))) void*)la1, 16, 0, 0);
        __builtin_amdgcn_global_load_lds((const __attribute__((address_space(1))) void*)gb0,
                                         (__attribute__((address_space(3))) void*)lb0, 16, 0, 0);
        __builtin_amdgcn_global_load_lds((const __attribute__((address_space(1))) void*)gb1,
                                         (__attribute__((address_space(3))) void*)lb1, 16, 0, 0);
        ga0 += 32; ga1 += 32; gb0 += 32; gb1 += 32;
        __syncthreads();

        half8 a[4], b[4];
#pragma unroll
        for (int mi = 0; mi < 4; ++mi) a[mi] = *(const half8*)&Ah[aoff + mi * 512];
#pragma unroll
        for (int ni = 0; ni < 4; ++ni) b[ni] = *(const half8*)&Bh[boff + ni * 512];
        // swapped operands: rows of D <- n (from Bt), cols of D <- m
#pragma unroll
        for (int mi = 0; mi < 4; ++mi)
#pragma unroll
            for (int ni = 0; ni < 4; ++ni)
                acc[mi][ni] = __builtin_amdgcn_mfma_f32_16x16x32_f16(
                    b[ni], a[mi], acc[mi][ni], 0, 0, 0);
    }

    // lane's m = col side (lane&15), n = row side ((lane>>4)*4 + r)
    const int mLane = mBase + wm * 64 + (lane & 15);
    const int nLane = nBase + wn * 64 + (lane >> 4) * 4;
#pragma unroll
    for (int ni = 0; ni < 4; ++ni) {
        const int n0 = nLane + ni * 16;
        float4 bv = bias ? *(const float4*)&bias[n0] : make_float4(0.f, 0.f, 0.f, 0.f);
#pragma unroll
        for (int mi = 0; mi < 4; ++mi) {
            const int m = mLane + mi * 16;
            if (m < M) {
                floatx4 v = acc[mi][ni];
                if constexpr (sizeof(OutT) == 2) {
                    half4 h = { (_Float16)(v[0] + bv.x), (_Float16)(v[1] + bv.y),
                                (_Float16)(v[2] + bv.z), (_Float16)(v[3] + bv.w) };
                    *(half4*)&Cm[(size_t)m * Nd + n0] = h;
                } else {
                    float4 o = make_float4(v[0] + bv.x, v[1] + bv.y, v[2] + bv.z, v[3] + bv.w);
                    *(float4*)&Cm[(size_t)m * Nd + n0] = o;
                }
            }
        }
    }
}

// ---------------------------------------------------------------------------
// Column attention partials: block (w,nh,b), 64 thr. K fp16 LDS + fdot2,
// V fp32 LDS. Online softmax, unnormalized partial out.
// ---------------------------------------------------------------------------
__global__ __launch_bounds__(64) void col_attn(
    const _Float16* __restrict__ qkvh, float* __restrict__ Ocol,
    float* __restrict__ mcol, float* __restrict__ lcol)
{
    const int w = blockIdx.x, nh = blockIdx.y, b = blockIdx.z;
    __shared__ __align__(16) _Float16 Kh[57 * HDd];
    __shared__ float Vf[57 * HDd];
    const int tid = threadIdx.x;

    for (int e = tid; e < 57 * 8; e += 64) {
        int j = e >> 3, c = e & 7;
        int n = (j == 0) ? 0 : ((j - 1) * Ws + w + 1);
        const _Float16* base = qkvh + (size_t)(b * Nt + n) * C3 + nh * HDd + c * 8;
        *(half8*)&Kh[j * HDd + c * 8] = *(const half8*)(base + Cc);
        half8 vv = *(const half8*)(base + 2 * Cc);
        float4 lo = { (float)vv[0], (float)vv[1], (float)vv[2], (float)vv[3] };
        float4 hi = { (float)vv[4], (float)vv[5], (float)vv[6], (float)vv[7] };
        *(float4*)&Vf[j * HDd + c * 8] = lo;
        *(float4*)&Vf[j * HDd + c * 8 + 4] = hi;
    }
    __syncthreads();

    if (tid < Hs) {
        const int h = tid;
        const int n = h * Ws + w + 1;
        const _Float16* qp = qkvh + (size_t)(b * Nt + n) * C3 + nh * HDd;
        half8 q8[8];
#pragma unroll
        for (int c = 0; c < 8; ++c) q8[c] = ((const half8*)qp)[c];

        float m = -INFINITY, l = 0.f;
        float4 O4[16] = {};

        for (int j = 0; j <= Hs; ++j) {
            const half8* kp = (const half8*)&Kh[j * HDd];
            float s0 = 0.f, s1 = 0.f, s2 = 0.f, s3 = 0.f;
#pragma unroll
            for (int c = 0; c < 8; ++c) {
                half8 kk = kp[c];
                const half2_* k2 = (const half2_*)&kk;
                const half2_* qq = (const half2_*)&q8[c];
                s0 = fdot2f(qq[0], k2[0], s0);
                s1 = fdot2f(qq[1], k2[1], s1);
                s2 = fdot2f(qq[2], k2[2], s2);
                s3 = fdot2f(qq[3], k2[3], s3);
            }
            float s = ((s0 + s1) + (s2 + s3)) * SCALE;
            float mn = fmaxf(m, s);
            float corr = __expf(m - mn);
            float p = __expf(s - mn);
            l = l * corr + p;
            const float4* vp = (const float4*)&Vf[j * HDd];
#pragma unroll
            for (int d4 = 0; d4 < 16; ++d4) {
                float4 vv = vp[d4];
                O4[d4].x = fmaf(O4[d4].x, corr, p * vv.x);
                O4[d4].y = fmaf(O4[d4].y, corr, p * vv.y);
                O4[d4].z = fmaf(O4[d4].z, corr, p * vv.z);
                O4[d4].w = fmaf(O4[d4].w, corr, p * vv.w);
            }
            m = mn;
        }
        const size_t qi = (size_t)((b * NHh + nh) * HW_ + h * Ws + w);
        mcol[qi] = m;
        lcol[qi] = l;
#pragma unroll
        for (int d4 = 0; d4 < 16; ++d4)
            *(float4*)&Ocol[qi * HDd + d4 * 4] = O4[d4];
    }
}

// ---------------------------------------------------------------------------
// Row attention + merge -> attH (fp16)
// ---------------------------------------------------------------------------
__global__ __launch_bounds__(64) void row_attn_merge(
    const _Float16* __restrict__ qkvh, const float* __restrict__ Ocol,
    const float* __restrict__ mcol, const float* __restrict__ lcol,
    _Float16* __restrict__ attH)
{
    const int h = blockIdx.x, nh = blockIdx.y, b = blockIdx.z;
    __shared__ __align__(16) _Float16 Kh[Ws * HDd];
    __shared__ float Vf[Ws * HDd];
    const int tid = threadIdx.x;

    for (int e = tid; e < Ws * 8; e += 64) {
        int j = e >> 3, c = e & 7;
        int n = h * Ws + j + 1;
        const _Float16* base = qkvh + (size_t)(b * Nt + n) * C3 + nh * HDd + c * 8;
        *(half8*)&Kh[j * HDd + c * 8] = *(const half8*)(base + Cc);
        half8 vv = *(const half8*)(base + 2 * Cc);
        float4 lo = { (float)vv[0], (float)vv[1], (float)vv[2], (float)vv[3] };
        float4 hi = { (float)vv[4], (float)vv[5], (float)vv[6], (float)vv[7] };
        *(float4*)&Vf[j * HDd + c * 8] = lo;
        *(float4*)&Vf[j * HDd + c * 8 + 4] = hi;
    }
    __syncthreads();

    if (tid < Ws) {
        const int w = tid;
        const int n = h * Ws + w + 1;
        const _Float16* qp = qkvh + (size_t)(b * Nt + n) * C3 + nh * HDd;
        half8 q8[8];
#pragma unroll
        for (int c = 0; c < 8; ++c) q8[c] = ((const half8*)qp)[c];

        float m = -INFINITY, l = 0.f;
        float4 O4[16] = {};

        for (int j = 0; j < Ws; ++j) {
            if (j == w) continue;
            const half8* kp = (const half8*)&Kh[j * HDd];
            float s0 = 0.f, s1 = 0.f, s2 = 0.f, s3 = 0.f;
#pragma unroll
            for (int c = 0; c < 8; ++c) {
                half8 kk = kp[c];
                const half2_* k2 = (const half2_*)&kk;
                const half2_* qq = (const half2_*)&q8[c];
                s0 = fdot2f(qq[0], k2[0], s0);
                s1 = fdot2f(qq[1], k2[1], s1);
                s2 = fdot2f(qq[2], k2[2], s2);
                s3 = fdot2f(qq[3], k2[3], s3);
            }
            float s = ((s0 + s1) + (s2 + s3)) * SCALE;
            float mn = fmaxf(m, s);
            float corr = __expf(m - mn);
            float p = __expf(s - mn);
            l = l * corr + p;
            const float4* vp = (const float4*)&Vf[j * HDd];
#pragma unroll
            for (int d4 = 0; d4 < 16; ++d4) {
                float4 vv = vp[d4];
                O4[d4].x = fmaf(O4[d4].x, corr, p * vv.x);
                O4[d4].y = fmaf(O4[d4].y, corr, p * vv.y);
                O4[d4].z = fmaf(O4[d4].z, corr, p * vv.z);
                O4[d4].w = fmaf(O4[d4].w, corr, p * vv.w);
            }
            m = mn;
        }

        const size_t qi = (size_t)((b * NHh + nh) * HW_ + h * Ws + w);
        const float mc = mcol[qi], lc = lcol[qi];
        const float mn = fmaxf(mc, m);
        const float fc = __expf(mc - mn);
        const float fr = __expf(m - mn);
        const float inv = 1.f / (lc * fc + l * fr);
        _Float16* op = attH + (size_t)(b * Nt + n) * Cc + nh * HDd;
        const float* ocp = Ocol + qi * HDd;
#pragma unroll
        for (int d4 = 0; d4 < 16; ++d4) {
            float4 oc = *(const float4*)(ocp + d4 * 4);
            half4 r = { (_Float16)((oc.x * fc + O4[d4].x * fr) * inv),
                        (_Float16)((oc.y * fc + O4[d4].y * fr) * inv),
                        (_Float16)((oc.z * fc + O4[d4].z * fr) * inv),
                        (_Float16)((oc.w * fc + O4[d4].w * fr) * inv) };
            *(half4*)(op + d4 * 4) = r;
        }
    }
}

// ---------------------------------------------------------------------------
// Cls-token attention, 4-way key-split for occupancy. Partial (m,l,O) per
// (b,nh,s); merged by cls_merge.
// ---------------------------------------------------------------------------
__global__ __launch_bounds__(1024) void cls_part(
    const _Float16* __restrict__ qkvh, float* __restrict__ P)
{
    const int nh = blockIdx.x, b = blockIdx.y, sidx = blockIdx.z;
    const int j0 = sidx * 785, j1 = min(Nt, j0 + 785);
    const int tid = threadIdx.x;
    const int lane = tid & 63, wv = tid >> 6;

    const float qd = (float)qkvh[(size_t)(b * Nt) * C3 + nh * HDd + lane];
    float m = -INFINITY, l = 0.f, Od = 0.f;

    for (int j = j0 + wv; j < j1; j += 16) {
        const _Float16* base = qkvh + (size_t)(b * Nt + j) * C3 + nh * HDd;
        float prod = qd * (float)base[Cc + lane];
#pragma unroll
        for (int off = 32; off >= 1; off >>= 1)
            prod += __shfl_xor(prod, off, 64);
        float s = prod * SCALE;
        float mn = fmaxf(m, s);
        float corr = __expf(m - mn);
        float p = __expf(s - mn);
        l = l * corr + p;
        Od = fmaf(Od, corr, p * (float)base[2 * Cc + lane]);
        m = mn;
    }

    __shared__ float sm[16], sl[16], sO[16][64];
    if (lane == 0) { sm[wv] = m; sl[wv] = l; }
    sO[wv][lane] = Od;
    __syncthreads();

    if (tid < 64) {
        float M2 = sm[0];
#pragma unroll
        for (int i = 1; i < 16; ++i) M2 = fmaxf(M2, sm[i]);
        float L = 0.f, OO = 0.f;
#pragma unroll
        for (int i = 0; i < 16; ++i) {
            float f = __expf(sm[i] - M2);
            L += sl[i] * f;
            OO += sO[i][tid] * f;
        }
        float* pp = P + (size_t)((b * NHh + nh) * 4 + sidx) * 66;
        if (tid == 0) { pp[0] = M2; pp[1] = L; }
        pp[2 + tid] = OO;
    }
}

__global__ __launch_bounds__(64) void cls_merge(
    const float* __restrict__ P, _Float16* __restrict__ attH)
{
    const int nh = blockIdx.x, b = blockIdx.y;
    const int tid = threadIdx.x;
    const float* p0 = P + (size_t)(b * NHh + nh) * 4 * 66;
    float M2 = fmaxf(fmaxf(p0[0], p0[66]), fmaxf(p0[132], p0[198]));
    float L = 0.f, OO = 0.f;
#pragma unroll
    for (int i = 0; i < 4; ++i) {
        const float* pp = p0 + i * 66;
        float f = __expf(pp[0] - M2);
        L += pp[1] * f;
        OO += pp[2 + tid] * f;
    }
    attH[(size_t)(b * Nt) * Cc + nh * HDd + tid] = (_Float16)(OO / L);
}

// ---------------------------------------------------------------------------
extern "C" void kernel_launch(void* const* d_in, const int* in_sizes, int n_in,
                              void* d_out, int out_size, void* d_ws, size_t ws_size,
                              hipStream_t stream)
{
    const float* x     = (const float*)d_in[0];
    const float* Wqkv  = (const float*)d_in[1];
    const float* Wproj = (const float*)d_in[2];
    const float* bproj = (const float*)d_in[3];
    float* out = (float*)d_out;

    _Float16* qkvh;   hipGetSymbolAddress((void**)&qkvh,   HIP_SYMBOL(g_qkvh));
    float*    Ocol;   hipGetSymbolAddress((void**)&Ocol,   HIP_SYMBOL(g_Ocol));
    float*    mcol;   hipGetSymbolAddress((void**)&mcol,   HIP_SYMBOL(g_mcol));
    float*    lcol;   hipGetSymbolAddress((void**)&lcol,   HIP_SYMBOL(g_lcol));
    _Float16* xh;     hipGetSymbolAddress((void**)&xh,     HIP_SYMBOL(g_xh));
    _Float16* attH;   hipGetSymbolAddress((void**)&attH,   HIP_SYMBOL(g_attH));
    _Float16* WqkvT;  hipGetSymbolAddress((void**)&WqkvT,  HIP_SYMBOL(g_WqkvT));
    _Float16* WprojT; hipGetSymbolAddress((void**)&WprojT, HIP_SYMBOL(g_WprojT));
    float*    clsP;   hipGetSymbolAddress((void**)&clsP,   HIP_SYMBOL(g_clsP));

    // 0) prep
    cvt_f16<<<4096, 256, 0, stream>>>(x, xh, (Mrows * Cc) / 4);
    transpose_f16<<<dim3(C3 / 32, Cc / 32), 256, 0, stream>>>(Wqkv, WqkvT, Cc, C3);
    transpose_f16<<<dim3(Cc / 32, Cc / 32), 256, 0, stream>>>(Wproj, WprojT, Cc, Cc);

    // 1) qkv = x @ W_qkv  (fp16 out)
    gemm_f16<_Float16><<<dim3(C3 / 128, Mpad / 128), 256, 0, stream>>>(
        xh, WqkvT, nullptr, qkvh, Mrows, C3, Cc);

    // 2) attention
    col_attn<<<dim3(Ws, NHh, B_), 64, 0, stream>>>(qkvh, Ocol, mcol, lcol);
    cls_part<<<dim3(NHh, B_, 4), 1024, 0, stream>>>(qkvh, clsP);
    cls_merge<<<dim3(NHh, B_), 64, 0, stream>>>(clsP, attH);
    row_attn_merge<<<dim3(Hs, NHh, B_), 64, 0, stream>>>(qkvh, Ocol, mcol, lcol, attH);

    // 3) out = attH @ W_proj + b_proj  (fp32 out)
    gemm_f16<float><<<dim3(Cc / 128, Mpad / 128), 256, 0, stream>>>(
        attH, WprojT, bproj, out, Mrows, Cc, Cc);
}